// Round 3
// baseline (4539.777 us; speedup 1.0000x reference)
//
#include <hip/hip_runtime.h>
#include <hip/hip_bf16.h>

// Model: B=2048, T=80, V=80, E=8, H=256, 2-layer LSTM + dense on last step.
// Phase split: lstm1 over all T (h1 -> ws as bf16), then lstm2 + dense.
// Each block owns 8 batch rows; recurrence is row-independent so no
// inter-block sync is ever needed. Weights reordered once per launch into
// gate-interleaved float4 so the inner loop is 1 coalesced float4 load +
// 16 FMAs per k per row-group.

#define BB 2048
#define TT 80
#define VV 80
#define EE 8
#define HH 256

__device__ __forceinline__ float sigf(float x) { return 1.0f / (1.0f + __expf(-x)); }

// Wt[k*H + d] = (W[k,d], W[k,H+d], W[k,2H+d], W[k,3H+d])  (i,j,f,o for dim d)
__global__ void reorder_w(const float* __restrict__ W, float4* __restrict__ Wt, int K) {
    int idx = blockIdx.x * blockDim.x + threadIdx.x;
    int k = idx >> 8, d = idx & (HH - 1);
    if (k < K) {
        const float* row = W + (size_t)k * (4 * HH);
        Wt[idx] = make_float4(row[d], row[d + HH], row[d + 2 * HH], row[d + 3 * HH]);
    }
}

__global__ __launch_bounds__(512) void lstm1_kernel(
    const int* __restrict__ feats, const float* __restrict__ emb,
    const float4* __restrict__ W1t, const float* __restrict__ b1,
    __hip_bfloat16* __restrict__ h1out)
{
    __shared__ float xcat[8][EE + HH];   // [row][x(8) | h(256)]
    const int tid = threadIdx.x;
    const int d = tid & (HH - 1);
    const int rh = tid >> 8;             // 0/1 -> rows 0-3 / 4-7
    const int rbase = rh * 4;
    const int brow = blockIdx.x * 8;

    #pragma unroll
    for (int rr = 0; rr < 4; ++rr) xcat[rbase + rr][EE + d] = 0.0f;
    if (tid < 64) {
        int r = tid >> 3, e = tid & 7;
        int f = feats[(size_t)(brow + r) * TT];
        xcat[r][e] = emb[f * EE + e];
    }
    float c[4] = {0.f, 0.f, 0.f, 0.f};
    const float bi = b1[d], bj = b1[HH + d], bfg = b1[2 * HH + d] + 1.0f, bo = b1[3 * HH + d];
    __syncthreads();

    for (int t = 0; t < TT; ++t) {
        float acc[4][4];
        #pragma unroll
        for (int r = 0; r < 4; ++r) { acc[r][0] = bi; acc[r][1] = bj; acc[r][2] = bfg; acc[r][3] = bo; }

        #pragma unroll 2
        for (int k = 0; k < EE + HH; k += 4) {
            float4 w0 = W1t[(k + 0) * HH + d];
            float4 w1 = W1t[(k + 1) * HH + d];
            float4 w2 = W1t[(k + 2) * HH + d];
            float4 w3 = W1t[(k + 3) * HH + d];
            #pragma unroll
            for (int r = 0; r < 4; ++r) {
                float4 x = *reinterpret_cast<const float4*>(&xcat[rbase + r][k]);
                acc[r][0] = fmaf(x.x, w0.x, acc[r][0]);
                acc[r][1] = fmaf(x.x, w0.y, acc[r][1]);
                acc[r][2] = fmaf(x.x, w0.z, acc[r][2]);
                acc[r][3] = fmaf(x.x, w0.w, acc[r][3]);
                acc[r][0] = fmaf(x.y, w1.x, acc[r][0]);
                acc[r][1] = fmaf(x.y, w1.y, acc[r][1]);
                acc[r][2] = fmaf(x.y, w1.z, acc[r][2]);
                acc[r][3] = fmaf(x.y, w1.w, acc[r][3]);
                acc[r][0] = fmaf(x.z, w2.x, acc[r][0]);
                acc[r][1] = fmaf(x.z, w2.y, acc[r][1]);
                acc[r][2] = fmaf(x.z, w2.z, acc[r][2]);
                acc[r][3] = fmaf(x.z, w2.w, acc[r][3]);
                acc[r][0] = fmaf(x.w, w3.x, acc[r][0]);
                acc[r][1] = fmaf(x.w, w3.y, acc[r][1]);
                acc[r][2] = fmaf(x.w, w3.z, acc[r][2]);
                acc[r][3] = fmaf(x.w, w3.w, acc[r][3]);
            }
        }

        float hv[4];
        #pragma unroll
        for (int r = 0; r < 4; ++r) {
            float ii = sigf(acc[r][0]);
            float jj = tanhf(acc[r][1]);
            float ff = sigf(acc[r][2]);   // forget bias already folded
            float oo = sigf(acc[r][3]);
            c[r] = c[r] * ff + ii * jj;
            hv[r] = tanhf(c[r]) * oo;
        }
        __syncthreads();
        #pragma unroll
        for (int r = 0; r < 4; ++r) {
            xcat[rbase + r][EE + d] = hv[r];
            h1out[((size_t)t * BB + brow + rbase + r) * HH + d] = __float2bfloat16(hv[r]);
        }
        if (t + 1 < TT && tid < 64) {
            int r = tid >> 3, e = tid & 7;
            int f = feats[(size_t)(brow + r) * TT + (t + 1)];
            xcat[r][e] = emb[f * EE + e];
        }
        __syncthreads();
    }
}

__global__ __launch_bounds__(512) void lstm2_kernel(
    const __hip_bfloat16* __restrict__ h1in, const float4* __restrict__ W2t,
    const float* __restrict__ b2, const float* __restrict__ Wd,
    const float* __restrict__ bd, float* __restrict__ out)
{
    __shared__ float xcat[8][2 * HH];    // [row][h1(256) | h2(256)]
    const int tid = threadIdx.x;
    const int d = tid & (HH - 1);
    const int rh = tid >> 8;
    const int rbase = rh * 4;
    const int brow = blockIdx.x * 8;

    #pragma unroll
    for (int rr = 0; rr < 4; ++rr) {
        xcat[rbase + rr][HH + d] = 0.0f;
        xcat[rbase + rr][d] =
            __bfloat162float(h1in[((size_t)(brow + rbase + rr)) * HH + d]);
    }
    float c[4] = {0.f, 0.f, 0.f, 0.f};
    const float bi = b2[d], bj = b2[HH + d], bfg = b2[2 * HH + d] + 1.0f, bo = b2[3 * HH + d];
    __syncthreads();

    for (int t = 0; t < TT; ++t) {
        float acc[4][4];
        #pragma unroll
        for (int r = 0; r < 4; ++r) { acc[r][0] = bi; acc[r][1] = bj; acc[r][2] = bfg; acc[r][3] = bo; }

        #pragma unroll 2
        for (int k = 0; k < 2 * HH; k += 4) {
            float4 w0 = W2t[(k + 0) * HH + d];
            float4 w1 = W2t[(k + 1) * HH + d];
            float4 w2 = W2t[(k + 2) * HH + d];
            float4 w3 = W2t[(k + 3) * HH + d];
            #pragma unroll
            for (int r = 0; r < 4; ++r) {
                float4 x = *reinterpret_cast<const float4*>(&xcat[rbase + r][k]);
                acc[r][0] = fmaf(x.x, w0.x, acc[r][0]);
                acc[r][1] = fmaf(x.x, w0.y, acc[r][1]);
                acc[r][2] = fmaf(x.x, w0.z, acc[r][2]);
                acc[r][3] = fmaf(x.x, w0.w, acc[r][3]);
                acc[r][0] = fmaf(x.y, w1.x, acc[r][0]);
                acc[r][1] = fmaf(x.y, w1.y, acc[r][1]);
                acc[r][2] = fmaf(x.y, w1.z, acc[r][2]);
                acc[r][3] = fmaf(x.y, w1.w, acc[r][3]);
                acc[r][0] = fmaf(x.z, w2.x, acc[r][0]);
                acc[r][1] = fmaf(x.z, w2.y, acc[r][1]);
                acc[r][2] = fmaf(x.z, w2.z, acc[r][2]);
                acc[r][3] = fmaf(x.z, w2.w, acc[r][3]);
                acc[r][0] = fmaf(x.w, w3.x, acc[r][0]);
                acc[r][1] = fmaf(x.w, w3.y, acc[r][1]);
                acc[r][2] = fmaf(x.w, w3.z, acc[r][2]);
                acc[r][3] = fmaf(x.w, w3.w, acc[r][3]);
            }
        }

        float hv[4];
        #pragma unroll
        for (int r = 0; r < 4; ++r) {
            float ii = sigf(acc[r][0]);
            float jj = tanhf(acc[r][1]);
            float ff = sigf(acc[r][2]);
            float oo = sigf(acc[r][3]);
            c[r] = c[r] * ff + ii * jj;
            hv[r] = tanhf(c[r]) * oo;
        }
        __syncthreads();
        #pragma unroll
        for (int r = 0; r < 4; ++r) xcat[rbase + r][HH + d] = hv[r];
        if (t + 1 < TT) {
            #pragma unroll
            for (int r = 0; r < 4; ++r)
                xcat[rbase + r][d] = __bfloat162float(
                    h1in[((size_t)(t + 1) * BB + brow + rbase + r) * HH + d]);
        }
        __syncthreads();
    }

    // dense epilogue: logits[r, v] = h2[r, :] @ Wd[:, v] + bd[v]
    for (int idx = tid; idx < 8 * VV; idx += 512) {
        int r = idx / VV, v = idx - r * VV;
        float s = bd[v];
        for (int dd = 0; dd < HH; ++dd)
            s = fmaf(xcat[r][HH + dd], Wd[dd * VV + v], s);
        out[(size_t)(brow + r) * VV + v] = s;
    }
}

extern "C" void kernel_launch(void* const* d_in, const int* in_sizes, int n_in,
                              void* d_out, int out_size, void* d_ws, size_t ws_size,
                              hipStream_t stream) {
    const int*   feats = (const int*)d_in[0];
    const float* emb   = (const float*)d_in[1];
    const float* W1    = (const float*)d_in[2];
    const float* b1    = (const float*)d_in[3];
    const float* W2    = (const float*)d_in[4];
    const float* b2    = (const float*)d_in[5];
    const float* Wd    = (const float*)d_in[6];
    const float* bd    = (const float*)d_in[7];
    float* out = (float*)d_out;

    char* ws = (char*)d_ws;
    float4* W1t = (float4*)(ws);                        // 264*256*16B = 1.06 MB
    float4* W2t = (float4*)(ws + (4u << 20));           // 2 MB
    __hip_bfloat16* h1 = (__hip_bfloat16*)(ws + (8u << 20)); // 80*2048*256*2B = 84 MB

    reorder_w<<<EE + HH, 256, 0, stream>>>(W1, W1t, EE + HH);
    reorder_w<<<2 * HH, 256, 0, stream>>>(W2, W2t, 2 * HH);
    lstm1_kernel<<<BB / 8, 512, 0, stream>>>(feats, emb, W1t, b1, h1);
    lstm2_kernel<<<BB / 8, 512, 0, stream>>>(h1, W2t, b2, Wd, bd, out);
}

// Round 6
// 3217.976 us; speedup vs baseline: 1.4108x; 1.4108x over previous
//
#include <hip/hip_runtime.h>
#include <hip/hip_bf16.h>

// B=2048, T=80, V=80, E=8, H=256. 2-layer LSTM + dense(last step).
// MFMA fp16, L2-streamed weights (register-resident is infeasible: W2 fp16 =
// 1MB > 512KB register file per CU). 128 blocks x 512 thr, M=16 rows/block.
// Weights pre-reordered into exact per-lane B-fragment stream order so the
// per-timestep weight walk is pure coalesced dwordx4 global->VGPR, 2-deep
// register double-buffered across column groups. No LDS for weights (each
// weight byte used by exactly one wave). h lives in LDS, XOR-swizzled.
// Layer-1 x-contribution folded into an 80-entry gate-interleaved table.
// lstm2 weight stream is ordered h2-half first so the h1 global loads (pa)
// have 64 MFMAs of latency cover before first use.

#define BB 2048
#define TT 80
#define VV 80
#define HH 256

typedef _Float16 half8 __attribute__((ext_vector_type(8)));
typedef float f32x4 __attribute__((ext_vector_type(4)));

__device__ __forceinline__ float sigf(float x) { return 1.0f / (1.0f + __expf(-x)); }
__device__ __forceinline__ float tanhfast(float x) { return 2.0f * sigf(2.0f * x) - 1.0f; }

// LDS h-tile: 16 rows x 512B, XOR-swizzle spreads the 16B column slots.
__device__ __forceinline__ int swz(int row, int kbyte) {
    return row * 512 + (kbyte ^ ((row & 7) << 4));
}

// table[(v*256+d)] = float4(i, j, f+1, o) gate biases for layer-1 x-path.
__global__ void prep_table(const float* __restrict__ emb, const float* __restrict__ W1,
                           const float* __restrict__ b1, float* __restrict__ tbl) {
    int v = blockIdx.x, d = threadIdx.x;
    float4 s;
    s.x = b1[d]; s.y = b1[256 + d]; s.z = b1[512 + d] + 1.0f; s.w = b1[768 + d];
    #pragma unroll
    for (int e = 0; e < 8; ++e) {
        float xv = emb[v * 8 + e];
        const float* wr = W1 + (size_t)e * 1024;
        s.x = fmaf(xv, wr[d], s.x);
        s.y = fmaf(xv, wr[256 + d], s.y);
        s.z = fmaf(xv, wr[512 + d], s.z);
        s.w = fmaf(xv, wr[768 + d], s.w);
    }
    ((float4*)tbl)[v * 256 + d] = s;
}

// B-fragment stream layout: halfIdx = (((w*8 + g*2 + j)*8 + kk)*64 + l)*8 + e
//   col  = g*256 + w*32 + j*16 + (l&15)
//   krow = 8 + kk*32 + (l>>4)*8 + e        (skip E rows of W1)
__global__ void prep_w1(const float* __restrict__ W1, _Float16* __restrict__ Wf) {
    int tid = blockIdx.x * 256 + threadIdx.x;                 // 32768
    int l = tid & 63, kk = (tid >> 6) & 7, j = (tid >> 9) & 1;
    int g = (tid >> 10) & 3, w = tid >> 12;
    int col = g * 256 + w * 32 + j * 16 + (l & 15);
    size_t base = ((size_t)((w * 8 + g * 2 + j) * 8 + kk) * 64 + l) * 8;
    #pragma unroll
    for (int e = 0; e < 8; ++e) {
        int krow = 8 + kk * 32 + (l >> 4) * 8 + e;
        Wf[base + e] = (_Float16)W1[(size_t)krow * 1024 + col];
    }
}

// 16 groups: halfIdx = (((w*16 + s*8 + g*2 + j)*8 + kk)*64 + l)*8 + e
//   s=0 -> h2 rows (256..511, consumed first from LDS),
//   s=1 -> h1 rows (0..255, consumed second so global pa loads can land).
__global__ void prep_w2(const float* __restrict__ W2, _Float16* __restrict__ Wf) {
    int tid = blockIdx.x * 256 + threadIdx.x;                 // 65536
    int l = tid & 63, kk = (tid >> 6) & 7, j = (tid >> 9) & 1;
    int g = (tid >> 10) & 3, s = (tid >> 12) & 1, w = tid >> 13;
    int col = g * 256 + w * 32 + j * 16 + (l & 15);
    size_t base = ((size_t)((w * 16 + s * 8 + g * 2 + j) * 8 + kk) * 64 + l) * 8;
    #pragma unroll
    for (int e = 0; e < 8; ++e) {
        int krow = (1 - s) * 256 + kk * 32 + (l >> 4) * 8 + e;
        Wf[base + e] = (_Float16)W2[(size_t)krow * 1024 + col];
    }
}

__global__ __launch_bounds__(512, 2) void lstm1_mfma(
    const int* __restrict__ feats, const float* __restrict__ tbl,
    const _Float16* __restrict__ Wf, _Float16* __restrict__ h1out)
{
    __shared__ char h_lds[8192];
    __shared__ int f_lds[16 * TT];
    const int tid = threadIdx.x, l = tid & 63, w = tid >> 6;
    const int brow = blockIdx.x * 16;
    const int row_a = l & 15, chunk = l >> 4;
    const int dim0 = w * 32 + (l & 15);

    for (int i = tid; i < 2048; i += 512) ((float*)h_lds)[i] = 0.f;
    for (int i = tid; i < 16 * TT; i += 512)
        f_lds[i] = feats[(size_t)(brow + i / TT) * TT + (i % TT)];

    float c[2][4] = {};
    const float4* tblv = (const float4*)tbl;
    __syncthreads();

    for (int t = 0; t < TT; ++t) {
        half8 a[8];
        #pragma unroll
        for (int kk = 0; kk < 8; ++kk)
            a[kk] = *(const half8*)(h_lds + swz(row_a, kk * 64 + chunk * 16));
        __syncthreads();                         // WAR: reads done before writes

        float4 tb[2][4];
        #pragma unroll
        for (int m = 0; m < 4; ++m) {
            int f = f_lds[(chunk * 4 + m) * TT + t];
            tb[0][m] = tblv[f * 256 + dim0];
            tb[1][m] = tblv[f * 256 + dim0 + 16];
        }

        f32x4 acc[8];
        #pragma unroll
        for (int n = 0; n < 8; ++n) acc[n] = (f32x4){0.f, 0.f, 0.f, 0.f};

        const half8* wp = (const half8*)Wf + (size_t)w * 8 * 512;
        half8 wbuf[2][8];
        #pragma unroll
        for (int kk = 0; kk < 8; ++kk) wbuf[0][kk] = wp[(size_t)kk * 64 + l];
        #pragma unroll
        for (int gid = 0; gid < 8; ++gid) {
            const int cur = gid & 1;
            if (gid < 7) {
                #pragma unroll
                for (int kk = 0; kk < 8; ++kk)
                    wbuf[cur ^ 1][kk] = wp[(size_t)((gid + 1) * 8 + kk) * 64 + l];
            }
            #pragma unroll
            for (int kk = 0; kk < 8; ++kk)
                acc[gid] = __builtin_amdgcn_mfma_f32_16x16x32_f16(
                    a[kk], wbuf[cur][kk], acc[gid], 0, 0, 0);
        }

        #pragma unroll
        for (int j = 0; j < 2; ++j) {
            const int D = dim0 + j * 16;
            #pragma unroll
            for (int m = 0; m < 4; ++m) {
                const int R = chunk * 4 + m;
                float zi = acc[j][m]     + tb[j][m].x;
                float zj = acc[2 + j][m] + tb[j][m].y;
                float zf = acc[4 + j][m] + tb[j][m].z;   // +1 folded
                float zo = acc[6 + j][m] + tb[j][m].w;
                c[j][m] = c[j][m] * sigf(zf) + sigf(zi) * tanhfast(zj);
                float hv = tanhfast(c[j][m]) * sigf(zo);
                *(_Float16*)(h_lds + swz(R, D * 2)) = (_Float16)hv;
                h1out[((size_t)t * BB + brow + R) * HH + D] = (_Float16)hv;
            }
        }
        __syncthreads();                         // RAW: h(t) visible
    }
}

__global__ __launch_bounds__(512, 2) void lstm2_mfma(
    const _Float16* __restrict__ h1, const _Float16* __restrict__ Wf,
    const float* __restrict__ b2, const float* __restrict__ Wd,
    const float* __restrict__ bd, float* __restrict__ out)
{
    __shared__ char h_lds[8192];
    const int tid = threadIdx.x, l = tid & 63, w = tid >> 6;
    const int brow = blockIdx.x * 16;
    const int row_a = l & 15, chunk = l >> 4;
    const int dim0 = w * 32 + (l & 15);

    for (int i = tid; i < 2048; i += 512) ((float*)h_lds)[i] = 0.f;

    float bv[2][4];
    #pragma unroll
    for (int j = 0; j < 2; ++j)
        #pragma unroll
        for (int g = 0; g < 4; ++g)
            bv[j][g] = b2[g * 256 + dim0 + j * 16] + (g == 2 ? 1.0f : 0.0f);

    float c[2][4] = {};
    __syncthreads();

    for (int t = 0; t < TT; ++t) {
        half8 a2[8];
        #pragma unroll
        for (int kk = 0; kk < 8; ++kk)
            a2[kk] = *(const half8*)(h_lds + swz(row_a, kk * 64 + chunk * 16));
        __syncthreads();                         // WAR

        // h1_t A-frags from global (L3-resident); consumed in the SECOND
        // half of the weight stream, so ~64 MFMAs cover the load latency.
        half8 pa[8];
        const _Float16* hp = h1 + ((size_t)t * BB + brow + row_a) * HH + chunk * 8;
        #pragma unroll
        for (int kk = 0; kk < 8; ++kk)
            pa[kk] = *(const half8*)(hp + kk * 32);

        f32x4 acc[8];
        #pragma unroll
        for (int n = 0; n < 8; ++n) acc[n] = (f32x4){0.f, 0.f, 0.f, 0.f};

        const half8* wp = (const half8*)Wf + (size_t)w * 16 * 512;
        half8 wbuf[2][8];
        #pragma unroll
        for (int kk = 0; kk < 8; ++kk) wbuf[0][kk] = wp[(size_t)kk * 64 + l];
        #pragma unroll
        for (int gid = 0; gid < 16; ++gid) {
            const int cur = gid & 1;
            if (gid < 15) {
                #pragma unroll
                for (int kk = 0; kk < 8; ++kk)
                    wbuf[cur ^ 1][kk] = wp[(size_t)((gid + 1) * 8 + kk) * 64 + l];
            }
            const int s = gid >> 3, acci = gid & 7;   // s=0: a2 (h2), s=1: pa (h1)
            #pragma unroll
            for (int kk = 0; kk < 8; ++kk)
                acc[acci] = __builtin_amdgcn_mfma_f32_16x16x32_f16(
                    s ? pa[kk] : a2[kk], wbuf[cur][kk], acc[acci], 0, 0, 0);
        }

        #pragma unroll
        for (int j = 0; j < 2; ++j) {
            const int D = dim0 + j * 16;
            #pragma unroll
            for (int m = 0; m < 4; ++m) {
                const int R = chunk * 4 + m;
                float zi = acc[j][m]     + bv[j][0];
                float zj = acc[2 + j][m] + bv[j][1];
                float zf = acc[4 + j][m] + bv[j][2];
                float zo = acc[6 + j][m] + bv[j][3];
                c[j][m] = c[j][m] * sigf(zf) + sigf(zi) * tanhfast(zj);
                float hv = tanhfast(c[j][m]) * sigf(zo);
                *(_Float16*)(h_lds + swz(R, D * 2)) = (_Float16)hv;
            }
        }
        __syncthreads();                         // RAW
    }

    // dense epilogue: out[r][v] = h2_last[r,:] @ Wd + bd
    for (int idx = tid; idx < 16 * VV; idx += 512) {
        int r = idx / VV, v = idx - r * VV;
        float s = bd[v];
        for (int d = 0; d < HH; ++d) {
            float h2 = (float)*(const _Float16*)(h_lds + swz(r, d * 2));
            s = fmaf(h2, Wd[(size_t)d * VV + v], s);
        }
        out[(size_t)(brow + r) * VV + v] = s;
    }
}

extern "C" void kernel_launch(void* const* d_in, const int* in_sizes, int n_in,
                              void* d_out, int out_size, void* d_ws, size_t ws_size,
                              hipStream_t stream) {
    const int*   feats = (const int*)d_in[0];
    const float* emb   = (const float*)d_in[1];
    const float* W1    = (const float*)d_in[2];
    const float* b1    = (const float*)d_in[3];
    const float* W2    = (const float*)d_in[4];
    const float* b2    = (const float*)d_in[5];
    const float* Wd    = (const float*)d_in[6];
    const float* bd    = (const float*)d_in[7];
    float* out = (float*)d_out;

    char* ws = (char*)d_ws;
    float*    tbl = (float*)ws;                        // 320 KB
    _Float16* W1f = (_Float16*)(ws + (512u << 10));    // 512 KB
    _Float16* W2f = (_Float16*)(ws + (1u << 20));      // 1 MB
    _Float16* h1  = (_Float16*)(ws + (2u << 20));      // 80 MB

    prep_table<<<VV, 256, 0, stream>>>(emb, W1, b1, tbl);
    prep_w1<<<128, 256, 0, stream>>>(W1, W1f);
    prep_w2<<<256, 256, 0, stream>>>(W2, W2f);
    lstm1_mfma<<<BB / 16, 512, 0, stream>>>(feats, tbl, W1f, h1);
    lstm2_mfma<<<BB / 16, 512, 0, stream>>>(h1, W2f, b2, Wd, bd, out);
}